// Round 1
// baseline (1335.321 us; speedup 1.0000x reference)
//
#include <hip/hip_runtime.h>

// out[o] = dot(in[o*I .. o*I+I], W[(o&(M-1))*I ..]) + bias[o&(M-1)]
// B=1024, M=2048, I=128. Memory-bound: stream 1 GiB of inputs once.

constexpr int Bb = 1024;
constexpr int Mm = 2048;
constexpr int Ii = 128;
constexpr long long TOTAL = (long long)Bb * Mm;   // 2^21 output elements

constexpr int BLOCK = 256;                        // 4 waves
constexpr int GRID = 8192;                        // 32768 waves total
constexpr int ELEMS_PER_WAVE = (int)(TOTAL / ((long long)GRID * (BLOCK / 64))); // 64

__global__ __launch_bounds__(BLOCK, 4)
void diag_dot_kernel(const float* __restrict__ in,
                     const float* __restrict__ W,
                     const float* __restrict__ bias,
                     float* __restrict__ out) {
    const int tid  = blockIdx.x * BLOCK + threadIdx.x;
    const int wave = tid >> 6;
    const int lane = threadIdx.x & 63;
    const int half = lane >> 5;   // which element of the pair this lane works on
    const int sub  = lane & 31;   // float4 slot within the 128-float row

    const long long start = (long long)wave * ELEMS_PER_WAVE;

    // 8 elements (4 pairs) per outer iteration -> 8 independent float4 loads in flight
    for (int e = 0; e < ELEMS_PER_WAVE; e += 8) {
        long long o[4];
        float4 x[4], w[4];
        int m[4];
#pragma unroll
        for (int j = 0; j < 4; ++j) {
            o[j] = start + e + 2 * j + half;
            m[j] = (int)(o[j] & (Mm - 1));
            const float4* ip = (const float4*)(in + o[j] * Ii) + sub;
            const float4* wp = (const float4*)(W + (long long)m[j] * Ii) + sub;
            x[j] = *ip;
            w[j] = *wp;
        }
#pragma unroll
        for (int j = 0; j < 4; ++j) {
            float acc = x[j].x * w[j].x + x[j].y * w[j].y
                      + x[j].z * w[j].z + x[j].w * w[j].w;
            // reduce across the 32-lane half-wave (xor masks < 32 stay in-group)
            acc += __shfl_xor(acc, 16);
            acc += __shfl_xor(acc, 8);
            acc += __shfl_xor(acc, 4);
            acc += __shfl_xor(acc, 2);
            acc += __shfl_xor(acc, 1);
            if (sub == 0) {
                out[o[j]] = acc + bias[m[j]];
            }
        }
    }
}

extern "C" void kernel_launch(void* const* d_in, const int* in_sizes, int n_in,
                              void* d_out, int out_size, void* d_ws, size_t ws_size,
                              hipStream_t stream) {
    const float* in   = (const float*)d_in[0];   // (B, M, I) fp32
    const float* W    = (const float*)d_in[1];   // (M, I) fp32
    const float* bias = (const float*)d_in[2];   // (M,) fp32
    float* out = (float*)d_out;                  // (B, M) fp32

    diag_dot_kernel<<<GRID, BLOCK, 0, stream>>>(in, W, bias, out);
}